// Round 1
// baseline (218.914 us; speedup 1.0000x reference)
//
#include <hip/hip_runtime.h>
#include <hip/hip_bf16.h>
#include <math.h>

#define NB 4
#define NL 512
#define ND 128
#define KSTR 136  // 128 + 8 bf16 pad -> 272B row stride, 16B aligned, ~2-way banks

typedef __attribute__((ext_vector_type(8))) short bf16x8;
typedef __attribute__((ext_vector_type(4))) float f32x4;

__device__ __forceinline__ short f2bf(float f) {
  union { float f; unsigned u; } un; un.f = f;
  unsigned r = un.u + 0x7FFFu + ((un.u >> 16) & 1u);  // RNE
  return (short)(r >> 16);
}

__global__ __launch_bounds__(256, 2) void unimol_coord_head(
    const float* __restrict__ x, const float* __restrict__ coord,
    const int* __restrict__ nodes, const float* __restrict__ ln_g,
    const float* __restrict__ ln_b, const float* __restrict__ w1,
    const float* __restrict__ b1, const float* __restrict__ w2,
    const float* __restrict__ b2, float* __restrict__ out)
{
  __shared__ __align__(16) short w1T[ND * KSTR];  // [n][k] bf16, gamma-folded
  __shared__ float b1p[ND];
  __shared__ float notpad[NL];
  __shared__ float coord_s[NL * 3];
  __shared__ float red[16];
  __shared__ float inv_atom_s;

  const int blk = blockIdx.x;
  const int bb = blk >> 9;
  const int lrow = blk & (NL - 1);
  const int tid = threadIdx.x;

  // pad row l: output = coord, contribution zero
  if (nodes[bb * NL + lrow] == 0) {
    if (tid < 3) out[(bb * NL + lrow) * 3 + tid] = coord[(bb * NL + lrow) * 3 + tid];
    return;
  }

  // ---- staging (once per block) ----
  for (int idx = tid; idx < ND * ND; idx += 256) {
    const int k = idx >> 7, n = idx & (ND - 1);
    w1T[n * KSTR + k] = f2bf(w1[idx] * ln_g[k]);   // fold gamma into w1
  }
  if (tid < ND) {                                   // fold beta into b1
    float s = b1[tid];
    for (int k = 0; k < ND; ++k) s = fmaf(ln_b[k], w1[k * ND + tid], s);
    b1p[tid] = s;
  }
  for (int j = tid; j < NL; j += 256) notpad[j] = (nodes[bb * NL + j] != 0) ? 1.0f : 0.0f;
  for (int j = tid; j < NL * 3; j += 256) coord_s[j] = coord[bb * (NL * 3) + j];
  __syncthreads();

  if (tid < 64) {  // wave0: atom_num (consumed only after the final barrier)
    float s = 0.f;
    for (int j = tid; j < NL; j += 64) s += notpad[j];
    #pragma unroll
    for (int m = 1; m <= 32; m <<= 1) s += __shfl_xor(s, m);
    if (tid == 0) inv_atom_s = 1.0f / s;
  }

  const int lane = tid & 63;
  const int wv = tid >> 6;
  const int c = lane & 15;   // A-row within tile / D-column within tile
  const int g = lane >> 4;   // k-group
  float b1r[8], w2r[8];
  #pragma unroll
  for (int nt = 0; nt < 8; ++nt) { b1r[nt] = b1p[16 * nt + c]; w2r[nt] = w2[16 * nt + c]; }
  const float b2v = b2[0];
  const float lanesel = (c == 0) ? 1.0f : 0.0f;

  float s0 = 0.f, sx = 0.f, sy = 0.f, sz = 0.f;
  const size_t xbase = (size_t)(bb * NL + lrow) * (NL * ND);

  for (int it = 0; it < 8; ++it) {
    const int mbase = (it << 6) + (wv << 4);
    // load this lane's slice of 16 rows of x, already in A-fragment layout:
    // row = c, k = 8*g + 32*ks + j
    const float* xr = x + xbase + (size_t)(mbase + c) * ND + 8 * g;
    f32x4 xv[8];
    #pragma unroll
    for (int ks = 0; ks < 4; ++ks) {
      xv[2 * ks]     = *reinterpret_cast<const f32x4*>(xr + 32 * ks);
      xv[2 * ks + 1] = *reinterpret_cast<const f32x4*>(xr + 32 * ks + 4);
    }
    // LayerNorm stats: 4 lanes (c, g=0..3) share one row -> xor 16, 32
    float sum = 0.f, sq = 0.f;
    #pragma unroll
    for (int q = 0; q < 8; ++q) {
      #pragma unroll
      for (int j = 0; j < 4; ++j) { const float e = xv[q][j]; sum += e; sq = fmaf(e, e, sq); }
    }
    sum += __shfl_xor(sum, 16); sum += __shfl_xor(sum, 32);
    sq  += __shfl_xor(sq, 16);  sq  += __shfl_xor(sq, 32);
    const float mu = sum * (1.0f / ND);
    const float rs = rsqrtf(fmaf(-mu, mu, sq * (1.0f / ND)) + 1e-5f);

    bf16x8 af[4];
    #pragma unroll
    for (int ks = 0; ks < 4; ++ks) {
      #pragma unroll
      for (int j = 0; j < 8; ++j) {
        const float e = (j < 4) ? xv[2 * ks][j] : xv[2 * ks + 1][j - 4];
        af[ks][j] = f2bf((e - mu) * rs);
      }
    }

    f32x4 acc[8];
    #pragma unroll
    for (int nt = 0; nt < 8; ++nt) acc[nt] = (f32x4){0.f, 0.f, 0.f, 0.f};
    #pragma unroll
    for (int ks = 0; ks < 4; ++ks) {
      const int koff = 8 * g + 32 * ks;
      #pragma unroll
      for (int nt = 0; nt < 8; ++nt) {
        const bf16x8 bf = *reinterpret_cast<const bf16x8*>(&w1T[(16 * nt + c) * KSTR + koff]);
        acc[nt] = __builtin_amdgcn_mfma_f32_16x16x32_bf16(af[ks], bf, acc[nt], 0, 0, 0);
      }
    }

    // epilogue: +b1, exact GELU, dot w2, reduce across the 16 columns
    float p[4] = {0.f, 0.f, 0.f, 0.f};
    #pragma unroll
    for (int nt = 0; nt < 8; ++nt) {
      #pragma unroll
      for (int i = 0; i < 4; ++i) {
        const float h = acc[nt][i] + b1r[nt];
        const float gl = 0.5f * h * (1.0f + erff(h * 0.70710678118f));
        p[i] = fmaf(gl, w2r[nt], p[i]);
      }
    }
    #pragma unroll
    for (int i = 0; i < 4; ++i) {
      p[i] += __shfl_xor(p[i], 1); p[i] += __shfl_xor(p[i], 2);
      p[i] += __shfl_xor(p[i], 4); p[i] += __shfl_xor(p[i], 8);
      const int m = mbase + 4 * g + i;        // D-layout row for this lane
      const float a = (p[i] + b2v) * notpad[m] * lanesel;
      s0 += a;
      sx = fmaf(a, coord_s[3 * m + 0], sx);
      sy = fmaf(a, coord_s[3 * m + 1], sy);
      sz = fmaf(a, coord_s[3 * m + 2], sz);
    }
  }

  #pragma unroll
  for (int m = 1; m <= 32; m <<= 1) {
    s0 += __shfl_xor(s0, m); sx += __shfl_xor(sx, m);
    sy += __shfl_xor(sy, m); sz += __shfl_xor(sz, m);
  }
  if (lane == 0) {
    red[wv * 4 + 0] = s0; red[wv * 4 + 1] = sx;
    red[wv * 4 + 2] = sy; red[wv * 4 + 3] = sz;
  }
  __syncthreads();
  if (tid == 0) {
    const float S0 = red[0] + red[4] + red[8] + red[12];
    const float SX = red[1] + red[5] + red[9] + red[13];
    const float SY = red[2] + red[6] + red[10] + red[14];
    const float SZ = red[3] + red[7] + red[11] + red[15];
    const float ia = inv_atom_s;
    const float cx = coord_s[3 * lrow + 0], cy = coord_s[3 * lrow + 1], cz = coord_s[3 * lrow + 2];
    float* o = out + (bb * NL + lrow) * 3;
    o[0] = cx + (SX - S0 * cx) * ia;
    o[1] = cy + (SY - S0 * cy) * ia;
    o[2] = cz + (SZ - S0 * cz) * ia;
  }
}

extern "C" void kernel_launch(void* const* d_in, const int* in_sizes, int n_in,
                              void* d_out, int out_size, void* d_ws, size_t ws_size,
                              hipStream_t stream) {
  const float* x     = (const float*)d_in[0];
  const float* coord = (const float*)d_in[1];
  const int*   nodes = (const int*)d_in[2];
  const float* ln_g  = (const float*)d_in[3];
  const float* ln_b  = (const float*)d_in[4];
  const float* w1    = (const float*)d_in[5];
  const float* b1    = (const float*)d_in[6];
  const float* w2    = (const float*)d_in[7];
  const float* b2    = (const float*)d_in[8];
  float* out = (float*)d_out;
  hipLaunchKernelGGL(unimol_coord_head, dim3(NB * NL), dim3(256), 0, stream,
                     x, coord, nodes, ln_g, ln_b, w1, b1, w2, b2, out);
}